// Round 10
// baseline (207.646 us; speedup 1.0000x reference)
//
#include <hip/hip_runtime.h>
#include <math.h>

#define NBLK 512   // bucketing blocks (each owns a contiguous edge chunk)

// ---------------- DPP helpers (full-rate VALU cross-lane, no LDS) ----------------

template<int CTRL>
__device__ __forceinline__ float dppf(float x) {
    return __int_as_float(__builtin_amdgcn_update_dpp(
        0, __float_as_int(x), CTRL, 0xF, 0xF, true));
}
// sum over 4-lane quad (lanes end with identical value)
__device__ __forceinline__ float quadsum(float x) {
    x += dppf<0xB1>(x);   // quad_perm xor 1
    x += dppf<0x4E>(x);   // quad_perm xor 2
    return x;
}
// sum over 16-lane group
__device__ __forceinline__ float sum16(float x) {
    x += dppf<0xB1>(x);
    x += dppf<0x4E>(x);
    x += dppf<0x141>(x);  // row_half_mirror
    x += dppf<0x140>(x);  // row_mirror
    return x;
}

// ---------------- init (replaces pathological hipMemsetAsync fills) ----------------

__global__ void k_init(float* __restrict__ sums, float* __restrict__ cnt, int gn) {
    int i = blockIdx.x * 256 + threadIdx.x;
    if (i < gn * 64) sums[i] = 0.f;
    if (i < gn) cnt[i] = 0.f;
}

// ---------------- Pass 1: per-(bucket,block) histogram, LDS only ----------------

__global__ __launch_bounds__(256) void k_hist(const int* __restrict__ tgt,
                                              int* __restrict__ gh,
                                              int e, int chunk, int nbuck) {
    __shared__ int lh[256];
    int tid = threadIdx.x, blk = blockIdx.x;
    lh[tid] = 0;
    __syncthreads();
    int lo = blk * chunk, hi = min(lo + chunk, e);
    for (int i = lo + tid; i < hi; i += 256)
        atomicAdd(&lh[tgt[i] >> 8], 1);
    __syncthreads();
    if (tid < nbuck) gh[tid * NBLK + blk] = lh[tid];
}

// ---------------- scan kernels (cell table; boff folded into consumers) ----------------

__global__ __launch_bounds__(256) void k_scanA(const int* __restrict__ deg,
                                               int* __restrict__ excl,
                                               int* __restrict__ bsum, int n) {
    int i = blockIdx.x * 256 + threadIdx.x;
    int lane = threadIdx.x & 63, wv = threadIdx.x >> 6;
    int v = (i < n) ? deg[i] : 0;
    int incl = v;
#pragma unroll
    for (int off = 1; off < 64; off <<= 1) {
        int t = __shfl_up(incl, off);
        if (lane >= off) incl += t;
    }
    __shared__ int ws[4];
    if (lane == 63) ws[wv] = incl;
    __syncthreads();
    int prefix = 0;
    for (int k = 0; k < wv; ++k) prefix += ws[k];
    if (i < n) excl[i] = prefix + incl - v;
    if (threadIdx.x == 255) bsum[blockIdx.x] = prefix + incl;
}

__global__ __launch_bounds__(256) void k_scanB(const int* __restrict__ bsum, int* __restrict__ boff,
                                               int nb) {
    __shared__ int ws[4];
    __shared__ int carry_s;
    int lane = threadIdx.x & 63, wv = threadIdx.x >> 6;
    if (threadIdx.x == 0) carry_s = 0;
    __syncthreads();
    for (int base = 0; base < nb; base += 256) {
        int i = base + threadIdx.x;
        int v = (i < nb) ? bsum[i] : 0;
        int incl = v;
#pragma unroll
        for (int off = 1; off < 64; off <<= 1) {
            int t = __shfl_up(incl, off);
            if (lane >= off) incl += t;
        }
        if (lane == 63) ws[wv] = incl;
        __syncthreads();
        int prefix = carry_s;
        for (int k = 0; k < wv; ++k) prefix += ws[k];
        if (i < nb) boff[i] = prefix + incl - v;
        __syncthreads();
        if (threadIdx.x == 255) carry_s = prefix + incl;
        __syncthreads();
    }
}

// ---------------- Pass 2: block-dense bucket placement (no global atomics) ----------------

__global__ __launch_bounds__(256) void k_binplace(const int* __restrict__ src,
                                                  const int* __restrict__ tgt,
                                                  const float* __restrict__ ea,
                                                  const float* __restrict__ x,
                                                  const int* __restrict__ gexcl,
                                                  const int* __restrict__ gboff,
                                                  float4* __restrict__ brec,
                                                  int* __restrict__ bmeta,
                                                  int e, int chunk, int nbuck) {
    __shared__ int loff[256];
    int tid = threadIdx.x, blk = blockIdx.x;
    if (tid < nbuck) {
        int cell = tid * NBLK + blk;
        loff[tid] = gexcl[cell] + gboff[cell >> 8];
    }
    __syncthreads();
    int lo = blk * chunk, hi = min(lo + chunk, e);
    for (int i = lo + tid; i < hi; i += 256) {
        int t = tgt[i], s = src[i];
        float2 ev = ((const float2*)ea)[i];
        float2 xv = *(const float2*)(x + 2 * (size_t)s);
        int dst = atomicAdd(&loff[t >> 8], 1);
        brec[dst] = make_float4(xv.x, xv.y, ev.x, ev.y);   // {x[src], ea}
        bmeta[dst] = (s & 0xFFFF) | ((t & 0xFF) << 16);    // src16 | tgt_local8
    }
}

// ---------------- fused: per-bucket degree hist + scan + rowp + CSR placement ----------------

__global__ __launch_bounds__(256) void k_place2(const int* __restrict__ gexcl,
                                                const int* __restrict__ gboff,
                                                const int* __restrict__ bmeta,
                                                const float4* __restrict__ brec,
                                                float4* __restrict__ col_rec,
                                                int* __restrict__ col_src,
                                                int* __restrict__ rowp,
                                                int n, int ntot, int e) {
    __shared__ int hist[256];
    __shared__ int pos[256];
    __shared__ int ws[4];
    int b = blockIdx.x, tid = threadIdx.x;
    int clo = b * NBLK, chi = clo + NBLK;
    int lo = gexcl[clo] + gboff[clo >> 8];
    int hi = (chi >= ntot) ? e : (gexcl[chi] + gboff[chi >> 8]);
    hist[tid] = 0;
    __syncthreads();
    for (int i = lo + tid; i < hi; i += 256)
        atomicAdd(&hist[(bmeta[i] >> 16) & 0xFF], 1);
    __syncthreads();
    int lane = tid & 63, wv = tid >> 6;
    int v = hist[tid];
    int incl = v;
#pragma unroll
    for (int off = 1; off < 64; off <<= 1) {
        int t = __shfl_up(incl, off);
        if (lane >= off) incl += t;
    }
    if (lane == 63) ws[wv] = incl;
    __syncthreads();
    int prefix = 0;
    for (int k = 0; k < wv; ++k) prefix += ws[k];
    int rp = lo + prefix + incl - v;
    int node = b * 256 + tid;
    if (node <= n) rowp[node] = rp;
    if (b == (int)gridDim.x - 1 && tid == 0) rowp[n] = hi;
    pos[tid] = rp;
    __syncthreads();
    for (int i = lo + tid; i < hi; i += 256) {
        int m = bmeta[i];
        float4 r = brec[i];
        int slot = atomicAdd(&pos[(m >> 16) & 0xFF], 1);
        col_rec[slot] = r;
        col_src[slot] = m & 0xFFFF;
    }
}

// ---------------- Layer 1: persistent-wave no-max softmax aggregation ----------------
// wave strides over nodes; lane l owns features 2l,2l+1; head = l>>2 (quad groups).

__global__ __launch_bounds__(256) void k_agg1(
    const float* __restrict__ x,
    const int* __restrict__ rowp,
    const float4* __restrict__ col_rec,
    const float* __restrict__ W_l1, const float* __restrict__ b_l1,
    const float* __restrict__ W_r1, const float* __restrict__ b_r1,
    const float* __restrict__ W_e1,
    const float* __restrict__ att1,
    const float* __restrict__ bias1,
    float* __restrict__ hpost,
    int n)
{
    int lane = threadIdx.x & 63;
    int f0 = 2 * lane, f1 = f0 + 1;
    // preamble: all per-lane weights hoisted out of the node loop
    float Wl00 = W_l1[f0], Wl10 = W_l1[128 + f0], bl0 = b_l1[f0];
    float Wl01 = W_l1[f1], Wl11 = W_l1[128 + f1], bl1 = b_l1[f1];
    float We00 = W_e1[f0], We10 = W_e1[128 + f0];
    float We01 = W_e1[f1], We11 = W_e1[128 + f1];
    float a0 = att1[f0], a1 = att1[f1];
    float Wr00 = W_r1[f0], Wr10 = W_r1[128 + f0], br0 = b_r1[f0];
    float Wr01 = W_r1[f1], Wr11 = W_r1[128 + f1], br1 = b_r1[f1];
    float bs0 = bias1[f0], bs1 = bias1[f1];
    bool b0 = (lane & 1) != 0, b1 = (lane & 2) != 0;
    int nw = (int)gridDim.x << 2;
    int v = __builtin_amdgcn_readfirstlane(((int)blockIdx.x << 2) | (threadIdx.x >> 6));

    for (; v < n; v += nw) {
        float xv0 = x[2 * v], xv1 = x[2 * v + 1];
        float xrA = fmaf(xv0, Wr00, fmaf(xv1, Wr10, br0));
        float xrB = fmaf(xv0, Wr01, fmaf(xv1, Wr11, br1));
        float lh = 0.f, acc0 = 0.f, acc1 = 0.f;
        int rs = rowp[v], re = rowp[v + 1];
        int cs = rs;
#define E1(K, R) \
        float xa##K = fmaf(R.x, Wl00, fmaf(R.y, Wl10, bl0)); \
        float xb##K = fmaf(R.x, Wl01, fmaf(R.y, Wl11, bl1)); \
        float s##K; { \
            float m0 = xa##K + xrA + R.z * We00 + R.w * We10; \
            float m1 = xb##K + xrB + R.z * We01 + R.w * We11; \
            s##K = quadsum(fmaf(fmaxf(m0, 0.2f * m0), a0, fmaxf(m1, 0.2f * m1) * a1)); \
        }
        for (; cs + 4 <= re; cs += 4) {
            float4 r0 = col_rec[cs + 0];
            float4 r1 = col_rec[cs + 1];
            float4 r2 = col_rec[cs + 2];
            float4 r3 = col_rec[cs + 3];
            E1(0, r0) E1(1, r1) E1(2, r2) E1(3, r3)
            float sel01 = b0 ? s1 : s0;
            float sel23 = b0 ? s3 : s2;
            float smy = b1 ? sel23 : sel01;     // lane's own edge score (k = lane&3)
            float p = __expf(smy);
            float p0 = dppf<0x00>(p), p1 = dppf<0x55>(p), p2 = dppf<0xAA>(p), p3 = dppf<0xFF>(p);
            lh += quadsum(p);
            acc0 = fmaf(p0, xa0, acc0); acc0 = fmaf(p1, xa1, acc0);
            acc0 = fmaf(p2, xa2, acc0); acc0 = fmaf(p3, xa3, acc0);
            acc1 = fmaf(p0, xb0, acc1); acc1 = fmaf(p1, xb1, acc1);
            acc1 = fmaf(p2, xb2, acc1); acc1 = fmaf(p3, xb3, acc1);
        }
#undef E1
        for (; cs < re; ++cs) {                 // tail (<=3 edges); s quad-uniform
            float4 r = col_rec[cs];
            float xa = fmaf(r.x, Wl00, fmaf(r.y, Wl10, bl0));
            float xb = fmaf(r.x, Wl01, fmaf(r.y, Wl11, bl1));
            float m0 = xa + xrA + r.z * We00 + r.w * We10;
            float m1 = xb + xrB + r.z * We01 + r.w * We11;
            float s = quadsum(fmaf(fmaxf(m0, 0.2f * m0), a0, fmaxf(m1, 0.2f * m1) * a1));
            float p = __expf(s);
            lh += p;
            acc0 = fmaf(p, xa, acc0);
            acc1 = fmaf(p, xb, acc1);
        }
        float r0o, r1o;
        if (re > rs) { float inv = 1.f / lh; r0o = acc0 * inv; r1o = acc1 * inv; }
        else { r0o = 0.f; r1o = 0.f; }
        r0o += bs0; r1o += bs1;
        r0o = (r0o > 0.f) ? r0o : (__expf(r0o) - 1.f);
        r1o = (r1o > 0.f) ? r1o : (__expf(r1o) - 1.f);
        *(float2*)(hpost + (size_t)v * 128 + f0) = make_float2(r0o, r1o);
    }
}

// ---------------- Layer 2 node transforms: register-tiled LDS GEMM ----------------

struct XF2Shared {
    float4 hs[64 * 32];
    float4 ws[128 * 16];
};

__device__ __forceinline__ void xf2_pass(XF2Shared& sm,
                                         const float* __restrict__ W,
                                         const float* __restrict__ b,
                                         float* __restrict__ out,
                                         int v0, int n, int t) {
    __syncthreads();
    {
        const float4* wsrc = (const float4*)W;
#pragma unroll
        for (int i = 0; i < 8; ++i) sm.ws[t + 256 * i] = wsrc[t + 256 * i];
    }
    __syncthreads();

    int lane = t & 63, w = t >> 6;
    int fg = lane & 3, ng = lane >> 2;
    int fq = 4 * w + fg;
    int hsw = ng & 7;

    float acc[4][4];
#pragma unroll
    for (int i = 0; i < 4; ++i)
#pragma unroll
        for (int c = 0; c < 4; ++c) acc[i][c] = 0.f;

    for (int kq = 0; kq < 32; ++kq) {
        float4 w0 = sm.ws[(4 * kq + 0) * 16 + fq];
        float4 w1 = sm.ws[(4 * kq + 1) * 16 + fq];
        float4 w2 = sm.ws[(4 * kq + 2) * 16 + fq];
        float4 w3 = sm.ws[(4 * kq + 3) * 16 + fq];
        int ks = kq ^ hsw;
        float4 h0 = sm.hs[(4 * ng + 0) * 32 + ks];
        float4 h1 = sm.hs[(4 * ng + 1) * 32 + ks];
        float4 h2 = sm.hs[(4 * ng + 2) * 32 + ks];
        float4 h3 = sm.hs[(4 * ng + 3) * 32 + ks];
#pragma unroll
        for (int i = 0; i < 4; ++i) {
            float4 h = (i == 0) ? h0 : (i == 1) ? h1 : (i == 2) ? h2 : h3;
            acc[i][0] += h.x * w0.x; acc[i][1] += h.x * w0.y; acc[i][2] += h.x * w0.z; acc[i][3] += h.x * w0.w;
            acc[i][0] += h.y * w1.x; acc[i][1] += h.y * w1.y; acc[i][2] += h.y * w1.z; acc[i][3] += h.y * w1.w;
            acc[i][0] += h.z * w2.x; acc[i][1] += h.z * w2.y; acc[i][2] += h.z * w2.z; acc[i][3] += h.z * w2.w;
            acc[i][0] += h.w * w3.x; acc[i][1] += h.w * w3.y; acc[i][2] += h.w * w3.z; acc[i][3] += h.w * w3.w;
        }
    }

    float4 bf = ((const float4*)b)[fq];
#pragma unroll
    for (int i = 0; i < 4; ++i) {
        int node = v0 + 4 * ng + i;
        if (node < n) {
            float4 r = make_float4(acc[i][0] + bf.x, acc[i][1] + bf.y,
                                   acc[i][2] + bf.z, acc[i][3] + bf.w);
            *(float4*)(out + (size_t)node * 64 + 4 * fq) = r;
        }
    }
}

__global__ __launch_bounds__(256) void k_transform2(
    const float* __restrict__ hpost,
    const float* __restrict__ W_l2, const float* __restrict__ b_l2,
    const float* __restrict__ W_r2, const float* __restrict__ b_r2,
    float* __restrict__ xl2, float* __restrict__ xr2, int n)
{
    __shared__ XF2Shared sm;
    int t = threadIdx.x;
    int v0 = blockIdx.x * 64;
    {
        int node = t >> 2, sub = t & 3;
        int sw = (node >> 2) & 7;
        bool valid = (v0 + node) < n;
        const float4* src = (const float4*)(hpost + (size_t)(v0 + node) * 128);
#pragma unroll
        for (int i = 0; i < 8; ++i) {
            int kq = sub + 4 * i;
            float4 val = valid ? src[kq] : make_float4(0.f, 0.f, 0.f, 0.f);
            sm.hs[node * 32 + (kq ^ sw)] = val;
        }
    }
    xf2_pass(sm, W_l2, b_l2, xl2, v0, n, t);
    xf2_pass(sm, W_r2, b_r2, xr2, v0, n, t);
}

// ---------------- Layer 2 aggregation: persistent-wave no-max softmax ----------------
// wave strides over nodes, lane = feature; head = lane>>4 (16-lane groups)

__global__ __launch_bounds__(256) void k_agg2(
    const float* __restrict__ xl2,
    const float* __restrict__ xr2,
    const int* __restrict__ rowp,
    const int* __restrict__ col_src,
    const float4* __restrict__ col_rec,
    const float* __restrict__ W_e2,
    const float* __restrict__ att2,
    const float* __restrict__ bias2,
    float* __restrict__ h2,
    int n)
{
    int lane = threadIdx.x & 63;
    float We0 = W_e2[lane], We1 = W_e2[64 + lane];
    float a = att2[lane];
    float bs = bias2[lane];
    bool b0 = (lane & 1) != 0, b1 = (lane & 2) != 0;
    const float2* eap = (const float2*)col_rec;   // {ea0,ea1} at odd float2 slots
    int nw = (int)gridDim.x << 2;
    int v = __builtin_amdgcn_readfirstlane(((int)blockIdx.x << 2) | (threadIdx.x >> 6));

    for (; v < n; v += nw) {
        float xr = xr2[(size_t)v * 64 + lane];
        float lh = 0.f, acc = 0.f;
        int rs = rowp[v], re = rowp[v + 1];
        int cs = rs;
#define E2(K, EV, XL) \
        float s##K; { \
            float m = XL + xr + EV.x * We0 + EV.y * We1; \
            s##K = sum16(fmaxf(m, 0.2f * m) * a); \
        }
        for (; cs + 4 <= re; cs += 4) {
            int u0 = col_src[cs], u1 = col_src[cs + 1], u2 = col_src[cs + 2], u3 = col_src[cs + 3];
            float2 e0 = eap[2 * cs + 1], e1 = eap[2 * cs + 3];
            float2 e2 = eap[2 * cs + 5], e3 = eap[2 * cs + 7];
            float xl0 = xl2[(size_t)u0 * 64 + lane];
            float xl1 = xl2[(size_t)u1 * 64 + lane];
            float xl2_ = xl2[(size_t)u2 * 64 + lane];
            float xl3 = xl2[(size_t)u3 * 64 + lane];
            E2(0, e0, xl0) E2(1, e1, xl1) E2(2, e2, xl2_) E2(3, e3, xl3)
            float sel01 = b0 ? s1 : s0;
            float sel23 = b0 ? s3 : s2;
            float smy = b1 ? sel23 : sel01;
            float p = __expf(smy);
            float p0 = dppf<0x00>(p), p1 = dppf<0x55>(p), p2 = dppf<0xAA>(p), p3 = dppf<0xFF>(p);
            lh += quadsum(p);
            acc = fmaf(p0, xl0, acc); acc = fmaf(p1, xl1, acc);
            acc = fmaf(p2, xl2_, acc); acc = fmaf(p3, xl3, acc);
        }
#undef E2
        for (; cs < re; ++cs) {
            int u = col_src[cs];
            float2 ev = eap[2 * cs + 1];
            float xl = xl2[(size_t)u * 64 + lane];
            float m = xl + xr + ev.x * We0 + ev.y * We1;
            float s = sum16(fmaxf(m, 0.2f * m) * a);
            float p = __expf(s);
            lh += p;
            acc = fmaf(p, xl, acc);
        }
        float r = (re > rs) ? acc / lh : 0.f;
        h2[(size_t)v * 64 + lane] = r + bs;
    }
}

// ---------------- Mean pool over graphs (batch sorted: segmented reduce) ----------------

__global__ __launch_bounds__(256) void k_pool2(const float* __restrict__ h2,
                                               const int* __restrict__ batch,
                                               float* __restrict__ sums, float* __restrict__ cnt,
                                               int n, int chunk) {
    int w = (blockIdx.x * blockDim.x + threadIdx.x) >> 6;
    int lane = threadIdx.x & 63;
    int start = w * chunk;
    if (start >= n) return;
    int end = min(n, start + chunk);
    int g = batch[start];
    float acc = 0.f;
    int c = 0;
    for (int v = start; v < end; ++v) {
        int bg = batch[v];
        if (bg != g) {
            atomicAdd(&sums[g * 64 + lane], acc);
            if (lane == 0) atomicAdd(&cnt[g], (float)c);
            acc = 0.f; c = 0; g = bg;
        }
        acc += h2[(size_t)v * 64 + lane];
        ++c;
    }
    atomicAdd(&sums[g * 64 + lane], acc);
    if (lane == 0) atomicAdd(&cnt[g], (float)c);
}

__global__ void k_final(const float* __restrict__ sums, const float* __restrict__ cnt,
                        float* __restrict__ out, int g) {
    int i = blockIdx.x * blockDim.x + threadIdx.x;
    if (i < g * 64) out[i] = sums[i] / fmaxf(cnt[i >> 6], 1.f);
}

// ---------------- launch ----------------

extern "C" void kernel_launch(void* const* d_in, const int* in_sizes, int n_in,
                              void* d_out, int out_size, void* d_ws, size_t ws_size,
                              hipStream_t stream) {
    const float* x     = (const float*)d_in[0];
    const float* ea    = (const float*)d_in[1];
    const float* W_l1  = (const float*)d_in[2];
    const float* b_l1  = (const float*)d_in[3];
    const float* W_r1  = (const float*)d_in[4];
    const float* b_r1  = (const float*)d_in[5];
    const float* W_e1  = (const float*)d_in[6];
    const float* att1  = (const float*)d_in[7];
    const float* bias1 = (const float*)d_in[8];
    const float* W_l2  = (const float*)d_in[9];
    const float* b_l2  = (const float*)d_in[10];
    const float* W_r2  = (const float*)d_in[11];
    const float* b_r2  = (const float*)d_in[12];
    const float* W_e2  = (const float*)d_in[13];
    const float* att2  = (const float*)d_in[14];
    const float* bias2 = (const float*)d_in[15];
    const int* eidx    = (const int*)d_in[16];
    const int* batch   = (const int*)d_in[17];

    int n = in_sizes[0] / 2;     // 50000
    int e = in_sizes[16] / 2;    // 800000
    int g = out_size / 64;       // 64
    const int* srcI = eidx;
    const int* tgtI = eidx + e;
    int nb = (n + 255) / 256;    // 196 buckets (256 nodes each)
    int ntot = nb * NBLK;        // cell table size
    int nb2 = (ntot + 255) / 256;
    int chunk = (e + NBLK - 1) / NBLK;

    char* w = (char*)d_ws;
    size_t off = 0;
    auto take = [&](size_t bytes) -> char* {
        size_t a = (off + 255) & ~(size_t)255;
        off = a + bytes;
        return w + a;
    };
    // region1: brec (sort phase) then hpost (agg1..transform2) then h2 (agg2..pool)
    char*   reg1    = take((size_t)n * 128 * 4);        // 25.6 MB >= e*16
    float4* brec    = (float4*)reg1;
    float*  hpost   = (float*)reg1;
    float*  h2      = hpost;
    // region2: bmeta (sort phase) then xl2 (transform2..agg2)
    char*   reg2    = take((size_t)n * 64 * 4);         // 12.8 MB >= e*4
    int*    bmeta   = (int*)reg2;
    float*  xl2     = (float*)reg2;

    float*  xr2     = (float*)take((size_t)n * 64 * 4);
    float4* col_rec = (float4*)take((size_t)e * 16);
    int*    col_src = (int*)take((size_t)e * 4);
    int*    rowp    = (int*)take((size_t)(n + 1) * 4);
    int*    gh      = (int*)take((size_t)ntot * 4);
    int*    gexcl   = (int*)take((size_t)(ntot + 1) * 4);
    int*    gbsum   = (int*)take((size_t)nb2 * 4);
    int*    gboff   = (int*)take((size_t)nb2 * 4);
    float*  sums    = (float*)take((size_t)g * 64 * 4);
    float*  cnt     = (float*)take((size_t)g * 4);

    k_init<<<(g * 64 + 255) / 256, 256, 0, stream>>>(sums, cnt, g);

    // dense two-pass counting sort by (bucket, block)
    k_hist<<<NBLK, 256, 0, stream>>>(tgtI, gh, e, chunk, nb);
    k_scanA<<<nb2, 256, 0, stream>>>(gh, gexcl, gbsum, ntot);
    k_scanB<<<1, 256, 0, stream>>>(gbsum, gboff, nb2);
    k_binplace<<<NBLK, 256, 0, stream>>>(srcI, tgtI, ea, x, gexcl, gboff, brec, bmeta,
                                         e, chunk, nb);
    k_place2<<<nb, 256, 0, stream>>>(gexcl, gboff, bmeta, brec, col_rec, col_src, rowp,
                                     n, ntot, e);

    k_agg1<<<1024, 256, 0, stream>>>(x, rowp, col_rec,
                                     W_l1, b_l1, W_r1, b_r1, W_e1, att1, bias1,
                                     hpost, n);
    int ntiles = (n + 63) / 64;
    k_transform2<<<ntiles, 256, 0, stream>>>(hpost, W_l2, b_l2, W_r2, b_r2, xl2, xr2, n);
    k_agg2<<<1024, 256, 0, stream>>>(xl2, xr2, rowp, col_src, col_rec,
                                     W_e2, att2, bias2, h2, n);

    int pool_waves = 1024;
    int pool_chunk = (n + pool_waves - 1) / pool_waves;
    k_pool2<<<pool_waves / 4, 256, 0, stream>>>(h2, batch, sums, cnt, n, pool_chunk);
    k_final<<<(g * 64 + 255) / 256, 256, 0, stream>>>(sums, cnt, (float*)d_out, g);
}

// Round 11
// 185.140 us; speedup vs baseline: 1.1216x; 1.1216x over previous
//
#include <hip/hip_runtime.h>
#include <math.h>

#define NBLK 512   // bucketing blocks (each owns a contiguous edge chunk)

// ---------------- DPP helpers (full-rate VALU cross-lane, no LDS) ----------------

template<int CTRL>
__device__ __forceinline__ float dppf(float x) {
    return __int_as_float(__builtin_amdgcn_update_dpp(
        0, __float_as_int(x), CTRL, 0xF, 0xF, true));
}
// sum over 4-lane quad (lanes end with identical value)
__device__ __forceinline__ float quadsum(float x) {
    x += dppf<0xB1>(x);   // quad_perm xor 1
    x += dppf<0x4E>(x);   // quad_perm xor 2
    return x;
}
// sum over 16-lane group
__device__ __forceinline__ float sum16(float x) {
    x += dppf<0xB1>(x);
    x += dppf<0x4E>(x);
    x += dppf<0x141>(x);  // row_half_mirror
    x += dppf<0x140>(x);  // row_mirror
    return x;
}

// ---------------- init (replaces pathological hipMemsetAsync fills) ----------------

__global__ void k_init(float* __restrict__ sums, float* __restrict__ cnt, int gn) {
    int i = blockIdx.x * 256 + threadIdx.x;
    if (i < gn * 64) sums[i] = 0.f;
    if (i < gn) cnt[i] = 0.f;
}

// ---------------- Pass 1: per-(bucket,block) histogram, LDS only ----------------

__global__ __launch_bounds__(256) void k_hist(const int* __restrict__ tgt,
                                              int* __restrict__ gh,
                                              int e, int chunk, int nbuck) {
    __shared__ int lh[256];
    int tid = threadIdx.x, blk = blockIdx.x;
    lh[tid] = 0;
    __syncthreads();
    int lo = blk * chunk, hi = min(lo + chunk, e);
    for (int i = lo + tid; i < hi; i += 256)
        atomicAdd(&lh[tgt[i] >> 8], 1);
    __syncthreads();
    if (tid < nbuck) gh[tid * NBLK + blk] = lh[tid];
}

// ---------------- scan kernels (cell table; boff folded into consumers) ----------------

__global__ __launch_bounds__(256) void k_scanA(const int* __restrict__ deg,
                                               int* __restrict__ excl,
                                               int* __restrict__ bsum, int n) {
    int i = blockIdx.x * 256 + threadIdx.x;
    int lane = threadIdx.x & 63, wv = threadIdx.x >> 6;
    int v = (i < n) ? deg[i] : 0;
    int incl = v;
#pragma unroll
    for (int off = 1; off < 64; off <<= 1) {
        int t = __shfl_up(incl, off);
        if (lane >= off) incl += t;
    }
    __shared__ int ws[4];
    if (lane == 63) ws[wv] = incl;
    __syncthreads();
    int prefix = 0;
    for (int k = 0; k < wv; ++k) prefix += ws[k];
    if (i < n) excl[i] = prefix + incl - v;
    if (threadIdx.x == 255) bsum[blockIdx.x] = prefix + incl;
}

__global__ __launch_bounds__(256) void k_scanB(const int* __restrict__ bsum, int* __restrict__ boff,
                                               int nb) {
    __shared__ int ws[4];
    __shared__ int carry_s;
    int lane = threadIdx.x & 63, wv = threadIdx.x >> 6;
    if (threadIdx.x == 0) carry_s = 0;
    __syncthreads();
    for (int base = 0; base < nb; base += 256) {
        int i = base + threadIdx.x;
        int v = (i < nb) ? bsum[i] : 0;
        int incl = v;
#pragma unroll
        for (int off = 1; off < 64; off <<= 1) {
            int t = __shfl_up(incl, off);
            if (lane >= off) incl += t;
        }
        if (lane == 63) ws[wv] = incl;
        __syncthreads();
        int prefix = carry_s;
        for (int k = 0; k < wv; ++k) prefix += ws[k];
        if (i < nb) boff[i] = prefix + incl - v;
        __syncthreads();
        if (threadIdx.x == 255) carry_s = prefix + incl;
        __syncthreads();
    }
}

// ---------------- Pass 2: block-dense bucket placement (no global atomics) ----------------

__global__ __launch_bounds__(256) void k_binplace(const int* __restrict__ src,
                                                  const int* __restrict__ tgt,
                                                  const float* __restrict__ ea,
                                                  const float* __restrict__ x,
                                                  const int* __restrict__ gexcl,
                                                  const int* __restrict__ gboff,
                                                  float4* __restrict__ brec,
                                                  int* __restrict__ bmeta,
                                                  int e, int chunk, int nbuck) {
    __shared__ int loff[256];
    int tid = threadIdx.x, blk = blockIdx.x;
    if (tid < nbuck) {
        int cell = tid * NBLK + blk;
        loff[tid] = gexcl[cell] + gboff[cell >> 8];
    }
    __syncthreads();
    int lo = blk * chunk, hi = min(lo + chunk, e);
    for (int i = lo + tid; i < hi; i += 256) {
        int t = tgt[i], s = src[i];
        float2 ev = ((const float2*)ea)[i];
        float2 xv = *(const float2*)(x + 2 * (size_t)s);
        int dst = atomicAdd(&loff[t >> 8], 1);
        brec[dst] = make_float4(xv.x, xv.y, ev.x, ev.y);   // {x[src], ea}
        bmeta[dst] = (s & 0xFFFF) | ((t & 0xFF) << 16);    // src16 | tgt_local8
    }
}

// ---------------- fused: per-bucket degree hist + scan + rowp + CSR placement ----------------

__global__ __launch_bounds__(256) void k_place2(const int* __restrict__ gexcl,
                                                const int* __restrict__ gboff,
                                                const int* __restrict__ bmeta,
                                                const float4* __restrict__ brec,
                                                float4* __restrict__ col_rec,
                                                int* __restrict__ col_src,
                                                int* __restrict__ rowp,
                                                int n, int ntot, int e) {
    __shared__ int hist[256];
    __shared__ int pos[256];
    __shared__ int ws[4];
    int b = blockIdx.x, tid = threadIdx.x;
    int clo = b * NBLK, chi = clo + NBLK;
    int lo = gexcl[clo] + gboff[clo >> 8];
    int hi = (chi >= ntot) ? e : (gexcl[chi] + gboff[chi >> 8]);
    hist[tid] = 0;
    __syncthreads();
    for (int i = lo + tid; i < hi; i += 256)
        atomicAdd(&hist[(bmeta[i] >> 16) & 0xFF], 1);
    __syncthreads();
    int lane = tid & 63, wv = tid >> 6;
    int v = hist[tid];
    int incl = v;
#pragma unroll
    for (int off = 1; off < 64; off <<= 1) {
        int t = __shfl_up(incl, off);
        if (lane >= off) incl += t;
    }
    if (lane == 63) ws[wv] = incl;
    __syncthreads();
    int prefix = 0;
    for (int k = 0; k < wv; ++k) prefix += ws[k];
    int rp = lo + prefix + incl - v;
    int node = b * 256 + tid;
    if (node <= n) rowp[node] = rp;
    if (b == (int)gridDim.x - 1 && tid == 0) rowp[n] = hi;
    pos[tid] = rp;
    __syncthreads();
    for (int i = lo + tid; i < hi; i += 256) {
        int m = bmeta[i];
        float4 r = brec[i];
        int slot = atomicAdd(&pos[(m >> 16) & 0xFF], 1);
        col_rec[slot] = r;
        col_src[slot] = m & 0xFFFF;
    }
}

// ---------------- Layer 1: no-max softmax aggregation (round-9 proven form) ----------------
// wave per node; lane l owns features 2l,2l+1; head = l>>2 (4-lane quad groups).

__global__ __launch_bounds__(256) void k_agg1(
    const float* __restrict__ x,
    const int* __restrict__ rowp,
    const float4* __restrict__ col_rec,
    const float* __restrict__ W_l1, const float* __restrict__ b_l1,
    const float* __restrict__ W_r1, const float* __restrict__ b_r1,
    const float* __restrict__ W_e1,
    const float* __restrict__ att1,
    const float* __restrict__ bias1,
    float* __restrict__ hpost,
    int n)
{
    int wid = (blockIdx.x * blockDim.x + threadIdx.x) >> 6;
    if (wid >= n) return;
    int v = __builtin_amdgcn_readfirstlane(wid);
    int lane = threadIdx.x & 63;
    int f0 = 2 * lane, f1 = 2 * lane + 1;

    float Wl00 = W_l1[f0], Wl10 = W_l1[128 + f0], bl0 = b_l1[f0];
    float Wl01 = W_l1[f1], Wl11 = W_l1[128 + f1], bl1 = b_l1[f1];
    float We00 = W_e1[f0], We10 = W_e1[128 + f0];
    float We01 = W_e1[f1], We11 = W_e1[128 + f1];
    float a0 = att1[f0], a1 = att1[f1];

    float xv0 = x[2 * v], xv1 = x[2 * v + 1];
    float xrA = xv0 * W_r1[f0] + xv1 * W_r1[128 + f0] + b_r1[f0];
    float xrB = xv0 * W_r1[f1] + xv1 * W_r1[128 + f1] + b_r1[f1];

    float lh = 0.f, acc0 = 0.f, acc1 = 0.f;
    int rs = rowp[v], re = rowp[v + 1];
    bool b0 = (lane & 1) != 0, b1 = (lane & 2) != 0;

    int cs = rs;
#define E1(K, R) \
    float xa##K = fmaf(R.x, Wl00, fmaf(R.y, Wl10, bl0)); \
    float xb##K = fmaf(R.x, Wl01, fmaf(R.y, Wl11, bl1)); \
    float s##K; { \
        float m0 = xa##K + xrA + R.z * We00 + R.w * We10; \
        float m1 = xb##K + xrB + R.z * We01 + R.w * We11; \
        s##K = quadsum(fmaf(fmaxf(m0, 0.2f * m0), a0, fmaxf(m1, 0.2f * m1) * a1)); \
    }
    for (; cs + 4 <= re; cs += 4) {
        float4 r0 = col_rec[cs + 0];
        float4 r1 = col_rec[cs + 1];
        float4 r2 = col_rec[cs + 2];
        float4 r3 = col_rec[cs + 3];
        E1(0, r0) E1(1, r1) E1(2, r2) E1(3, r3)
        float sel01 = b0 ? s1 : s0;
        float sel23 = b0 ? s3 : s2;
        float smy = b1 ? sel23 : sel01;     // lane's own edge score (k = lane&3)
        float p = __expf(smy);
        float p0 = dppf<0x00>(p), p1 = dppf<0x55>(p), p2 = dppf<0xAA>(p), p3 = dppf<0xFF>(p);
        lh += (p0 + p1) + (p2 + p3);
        acc0 += fmaf(p0, xa0, p1 * xa1) + fmaf(p2, xa2, p3 * xa3);
        acc1 += fmaf(p0, xb0, p1 * xb1) + fmaf(p2, xb2, p3 * xb3);
    }
#undef E1
    for (; cs < re; ++cs) {                 // tail (<=3 edges); s quad-uniform, no bcast
        float4 r = col_rec[cs];
        float xa = fmaf(r.x, Wl00, fmaf(r.y, Wl10, bl0));
        float xb = fmaf(r.x, Wl01, fmaf(r.y, Wl11, bl1));
        float m0 = xa + xrA + r.z * We00 + r.w * We10;
        float m1 = xb + xrB + r.z * We01 + r.w * We11;
        float s = quadsum(fmaf(fmaxf(m0, 0.2f * m0), a0, fmaxf(m1, 0.2f * m1) * a1));
        float p = __expf(s);
        lh += p;
        acc0 = fmaf(p, xa, acc0);
        acc1 = fmaf(p, xb, acc1);
    }

    float r0o, r1o;
    if (re > rs) { float inv = 1.f / lh; r0o = acc0 * inv; r1o = acc1 * inv; }
    else { r0o = 0.f; r1o = 0.f; }
    r0o += bias1[f0]; r1o += bias1[f1];
    r0o = (r0o > 0.f) ? r0o : (__expf(r0o) - 1.f);
    r1o = (r1o > 0.f) ? r1o : (__expf(r1o) - 1.f);
    *(float2*)(hpost + (size_t)v * 128 + f0) = make_float2(r0o, r1o);
}

// ---------------- Layer 2 node transforms: register-tiled LDS GEMM ----------------

struct XF2Shared {
    float4 hs[64 * 32];
    float4 ws[128 * 16];
};

__device__ __forceinline__ void xf2_pass(XF2Shared& sm,
                                         const float* __restrict__ W,
                                         const float* __restrict__ b,
                                         float* __restrict__ out,
                                         int v0, int n, int t) {
    __syncthreads();
    {
        const float4* wsrc = (const float4*)W;
#pragma unroll
        for (int i = 0; i < 8; ++i) sm.ws[t + 256 * i] = wsrc[t + 256 * i];
    }
    __syncthreads();

    int lane = t & 63, w = t >> 6;
    int fg = lane & 3, ng = lane >> 2;
    int fq = 4 * w + fg;
    int hsw = ng & 7;

    float acc[4][4];
#pragma unroll
    for (int i = 0; i < 4; ++i)
#pragma unroll
        for (int c = 0; c < 4; ++c) acc[i][c] = 0.f;

    for (int kq = 0; kq < 32; ++kq) {
        float4 w0 = sm.ws[(4 * kq + 0) * 16 + fq];
        float4 w1 = sm.ws[(4 * kq + 1) * 16 + fq];
        float4 w2 = sm.ws[(4 * kq + 2) * 16 + fq];
        float4 w3 = sm.ws[(4 * kq + 3) * 16 + fq];
        int ks = kq ^ hsw;
        float4 h0 = sm.hs[(4 * ng + 0) * 32 + ks];
        float4 h1 = sm.hs[(4 * ng + 1) * 32 + ks];
        float4 h2 = sm.hs[(4 * ng + 2) * 32 + ks];
        float4 h3 = sm.hs[(4 * ng + 3) * 32 + ks];
#pragma unroll
        for (int i = 0; i < 4; ++i) {
            float4 h = (i == 0) ? h0 : (i == 1) ? h1 : (i == 2) ? h2 : h3;
            acc[i][0] += h.x * w0.x; acc[i][1] += h.x * w0.y; acc[i][2] += h.x * w0.z; acc[i][3] += h.x * w0.w;
            acc[i][0] += h.y * w1.x; acc[i][1] += h.y * w1.y; acc[i][2] += h.y * w1.z; acc[i][3] += h.y * w1.w;
            acc[i][0] += h.z * w2.x; acc[i][1] += h.z * w2.y; acc[i][2] += h.z * w2.z; acc[i][3] += h.z * w2.w;
            acc[i][0] += h.w * w3.x; acc[i][1] += h.w * w3.y; acc[i][2] += h.w * w3.z; acc[i][3] += h.w * w3.w;
        }
    }

    float4 bf = ((const float4*)b)[fq];
#pragma unroll
    for (int i = 0; i < 4; ++i) {
        int node = v0 + 4 * ng + i;
        if (node < n) {
            float4 r = make_float4(acc[i][0] + bf.x, acc[i][1] + bf.y,
                                   acc[i][2] + bf.z, acc[i][3] + bf.w);
            *(float4*)(out + (size_t)node * 64 + 4 * fq) = r;
        }
    }
}

__global__ __launch_bounds__(256) void k_transform2(
    const float* __restrict__ hpost,
    const float* __restrict__ W_l2, const float* __restrict__ b_l2,
    const float* __restrict__ W_r2, const float* __restrict__ b_r2,
    float* __restrict__ xl2, float* __restrict__ xr2, int n)
{
    __shared__ XF2Shared sm;
    int t = threadIdx.x;
    int v0 = blockIdx.x * 64;
    {
        int node = t >> 2, sub = t & 3;
        int sw = (node >> 2) & 7;
        bool valid = (v0 + node) < n;
        const float4* src = (const float4*)(hpost + (size_t)(v0 + node) * 128);
#pragma unroll
        for (int i = 0; i < 8; ++i) {
            int kq = sub + 4 * i;
            float4 val = valid ? src[kq] : make_float4(0.f, 0.f, 0.f, 0.f);
            sm.hs[node * 32 + (kq ^ sw)] = val;
        }
    }
    xf2_pass(sm, W_l2, b_l2, xl2, v0, n, t);
    xf2_pass(sm, W_r2, b_r2, xr2, v0, n, t);
}

// ---------------- Layer 2 aggregation: no-max softmax (round-9 proven form) ----------------
// wave per node, lane = feature; head = lane>>4 (16-lane groups)

__global__ __launch_bounds__(256) void k_agg2(
    const float* __restrict__ xl2,
    const float* __restrict__ xr2,
    const int* __restrict__ rowp,
    const int* __restrict__ col_src,
    const float4* __restrict__ col_rec,
    const float* __restrict__ W_e2,
    const float* __restrict__ att2,
    const float* __restrict__ bias2,
    float* __restrict__ h2,
    int n)
{
    int wid = (blockIdx.x * blockDim.x + threadIdx.x) >> 6;
    if (wid >= n) return;
    int v = __builtin_amdgcn_readfirstlane(wid);
    int lane = threadIdx.x & 63;
    float We0 = W_e2[lane], We1 = W_e2[64 + lane];
    float a = att2[lane];
    float xr = xr2[(size_t)v * 64 + lane];
    float lh = 0.f, acc = 0.f;
    int rs = rowp[v], re = rowp[v + 1];
    const float2* eap = (const float2*)col_rec;   // {ea0,ea1} at odd float2 slots
    bool b0 = (lane & 1) != 0, b1 = (lane & 2) != 0;

    int cs = rs;
#define E2(K, EV, XL) \
    float s##K; { \
        float m = XL + xr + EV.x * We0 + EV.y * We1; \
        s##K = sum16(fmaxf(m, 0.2f * m) * a); \
    }
    for (; cs + 4 <= re; cs += 4) {
        int u0 = col_src[cs], u1 = col_src[cs + 1], u2 = col_src[cs + 2], u3 = col_src[cs + 3];
        float2 e0 = eap[2 * cs + 1], e1 = eap[2 * cs + 3];
        float2 e2 = eap[2 * cs + 5], e3 = eap[2 * cs + 7];
        float xl0 = xl2[(size_t)u0 * 64 + lane];
        float xl1 = xl2[(size_t)u1 * 64 + lane];
        float xl2_ = xl2[(size_t)u2 * 64 + lane];
        float xl3 = xl2[(size_t)u3 * 64 + lane];
        E2(0, e0, xl0) E2(1, e1, xl1) E2(2, e2, xl2_) E2(3, e3, xl3)
        float sel01 = b0 ? s1 : s0;
        float sel23 = b0 ? s3 : s2;
        float smy = b1 ? sel23 : sel01;
        float p = __expf(smy);
        float p0 = dppf<0x00>(p), p1 = dppf<0x55>(p), p2 = dppf<0xAA>(p), p3 = dppf<0xFF>(p);
        lh += (p0 + p1) + (p2 + p3);
        acc += fmaf(p0, xl0, p1 * xl1) + fmaf(p2, xl2_, p3 * xl3);
    }
#undef E2
    for (; cs < re; ++cs) {
        int u = col_src[cs];
        float2 ev = eap[2 * cs + 1];
        float xl = xl2[(size_t)u * 64 + lane];
        float m = xl + xr + ev.x * We0 + ev.y * We1;
        float s = sum16(fmaxf(m, 0.2f * m) * a);
        float p = __expf(s);
        lh += p;
        acc = fmaf(p, xl, acc);
    }
    float r = (re > rs) ? acc / lh : 0.f;
    h2[(size_t)v * 64 + lane] = r + bias2[lane];
}

// ---------------- Mean pool over graphs (batch sorted: segmented reduce) ----------------

__global__ __launch_bounds__(256) void k_pool2(const float* __restrict__ h2,
                                               const int* __restrict__ batch,
                                               float* __restrict__ sums, float* __restrict__ cnt,
                                               int n, int chunk) {
    int w = (blockIdx.x * blockDim.x + threadIdx.x) >> 6;
    int lane = threadIdx.x & 63;
    int start = w * chunk;
    if (start >= n) return;
    int end = min(n, start + chunk);
    int g = batch[start];
    float acc = 0.f;
    int c = 0;
    for (int v = start; v < end; ++v) {
        int bg = batch[v];
        if (bg != g) {
            atomicAdd(&sums[g * 64 + lane], acc);
            if (lane == 0) atomicAdd(&cnt[g], (float)c);
            acc = 0.f; c = 0; g = bg;
        }
        acc += h2[(size_t)v * 64 + lane];
        ++c;
    }
    atomicAdd(&sums[g * 64 + lane], acc);
    if (lane == 0) atomicAdd(&cnt[g], (float)c);
}

__global__ void k_final(const float* __restrict__ sums, const float* __restrict__ cnt,
                        float* __restrict__ out, int g) {
    int i = blockIdx.x * blockDim.x + threadIdx.x;
    if (i < g * 64) out[i] = sums[i] / fmaxf(cnt[i >> 6], 1.f);
}

// ---------------- launch ----------------

extern "C" void kernel_launch(void* const* d_in, const int* in_sizes, int n_in,
                              void* d_out, int out_size, void* d_ws, size_t ws_size,
                              hipStream_t stream) {
    const float* x     = (const float*)d_in[0];
    const float* ea    = (const float*)d_in[1];
    const float* W_l1  = (const float*)d_in[2];
    const float* b_l1  = (const float*)d_in[3];
    const float* W_r1  = (const float*)d_in[4];
    const float* b_r1  = (const float*)d_in[5];
    const float* W_e1  = (const float*)d_in[6];
    const float* att1  = (const float*)d_in[7];
    const float* bias1 = (const float*)d_in[8];
    const float* W_l2  = (const float*)d_in[9];
    const float* b_l2  = (const float*)d_in[10];
    const float* W_r2  = (const float*)d_in[11];
    const float* b_r2  = (const float*)d_in[12];
    const float* W_e2  = (const float*)d_in[13];
    const float* att2  = (const float*)d_in[14];
    const float* bias2 = (const float*)d_in[15];
    const int* eidx    = (const int*)d_in[16];
    const int* batch   = (const int*)d_in[17];

    int n = in_sizes[0] / 2;     // 50000
    int e = in_sizes[16] / 2;    // 800000
    int g = out_size / 64;       // 64
    const int* srcI = eidx;
    const int* tgtI = eidx + e;
    int nb = (n + 255) / 256;    // 196 buckets (256 nodes each)
    int ntot = nb * NBLK;        // cell table size
    int nb2 = (ntot + 255) / 256;
    int chunk = (e + NBLK - 1) / NBLK;

    char* w = (char*)d_ws;
    size_t off = 0;
    auto take = [&](size_t bytes) -> char* {
        size_t a = (off + 255) & ~(size_t)255;
        off = a + bytes;
        return w + a;
    };
    // region1: brec (sort phase) then hpost (agg1..transform2) then h2 (agg2..pool)
    char*   reg1    = take((size_t)n * 128 * 4);        // 25.6 MB >= e*16
    float4* brec    = (float4*)reg1;
    float*  hpost   = (float*)reg1;
    float*  h2      = hpost;
    // region2: bmeta (sort phase) then xl2 (transform2..agg2)
    char*   reg2    = take((size_t)n * 64 * 4);         // 12.8 MB >= e*4
    int*    bmeta   = (int*)reg2;
    float*  xl2     = (float*)reg2;

    float*  xr2     = (float*)take((size_t)n * 64 * 4);
    float4* col_rec = (float4*)take((size_t)e * 16);
    int*    col_src = (int*)take((size_t)e * 4);
    int*    rowp    = (int*)take((size_t)(n + 1) * 4);
    int*    gh      = (int*)take((size_t)ntot * 4);
    int*    gexcl   = (int*)take((size_t)(ntot + 1) * 4);
    int*    gbsum   = (int*)take((size_t)nb2 * 4);
    int*    gboff   = (int*)take((size_t)nb2 * 4);
    float*  sums    = (float*)take((size_t)g * 64 * 4);
    float*  cnt     = (float*)take((size_t)g * 4);

    k_init<<<(g * 64 + 255) / 256, 256, 0, stream>>>(sums, cnt, g);

    // dense two-pass counting sort by (bucket, block)
    k_hist<<<NBLK, 256, 0, stream>>>(tgtI, gh, e, chunk, nb);
    k_scanA<<<nb2, 256, 0, stream>>>(gh, gexcl, gbsum, ntot);
    k_scanB<<<1, 256, 0, stream>>>(gbsum, gboff, nb2);
    k_binplace<<<NBLK, 256, 0, stream>>>(srcI, tgtI, ea, x, gexcl, gboff, brec, bmeta,
                                         e, chunk, nb);
    k_place2<<<nb, 256, 0, stream>>>(gexcl, gboff, bmeta, brec, col_rec, col_src, rowp,
                                     n, ntot, e);

    int nwaveblocks = (n * 64 + 255) / 256;
    k_agg1<<<nwaveblocks, 256, 0, stream>>>(x, rowp, col_rec,
                                            W_l1, b_l1, W_r1, b_r1, W_e1, att1, bias1,
                                            hpost, n);
    int ntiles = (n + 63) / 64;
    k_transform2<<<ntiles, 256, 0, stream>>>(hpost, W_l2, b_l2, W_r2, b_r2, xl2, xr2, n);
    k_agg2<<<nwaveblocks, 256, 0, stream>>>(xl2, xr2, rowp, col_src, col_rec,
                                            W_e2, att2, bias2, h2, n);

    int pool_waves = 1024;
    int pool_chunk = (n + pool_waves - 1) / pool_waves;
    k_pool2<<<pool_waves / 4, 256, 0, stream>>>(h2, batch, sums, cnt, n, pool_chunk);
    k_final<<<(g * 64 + 255) / 256, 256, 0, stream>>>(sums, cnt, (float*)d_out, g);
}

// Round 12
// 178.189 us; speedup vs baseline: 1.1653x; 1.0390x over previous
//
#include <hip/hip_runtime.h>
#include <math.h>

#define NBLK 512   // bucketing blocks (each owns a contiguous edge chunk)

// ---------------- DPP helpers (full-rate VALU cross-lane, no LDS) ----------------

template<int CTRL>
__device__ __forceinline__ float dppf(float x) {
    return __int_as_float(__builtin_amdgcn_update_dpp(
        0, __float_as_int(x), CTRL, 0xF, 0xF, true));
}
// sum over 4-lane quad (lanes end with identical value)
__device__ __forceinline__ float quadsum(float x) {
    x += dppf<0xB1>(x);   // quad_perm xor 1
    x += dppf<0x4E>(x);   // quad_perm xor 2
    return x;
}
// sum over 16-lane group
__device__ __forceinline__ float sum16(float x) {
    x += dppf<0xB1>(x);
    x += dppf<0x4E>(x);
    x += dppf<0x141>(x);  // row_half_mirror
    x += dppf<0x140>(x);  // row_mirror
    return x;
}

// ---------------- init (replaces pathological hipMemsetAsync fills) ----------------

__global__ void k_init(float* __restrict__ sums, float* __restrict__ cnt, int gn) {
    int i = blockIdx.x * 256 + threadIdx.x;
    if (i < gn * 64) sums[i] = 0.f;
    if (i < gn) cnt[i] = 0.f;
}

// ---------------- Pass 1: per-(bucket,block) histogram, LDS only ----------------

__global__ __launch_bounds__(256) void k_hist(const int* __restrict__ tgt,
                                              int* __restrict__ gh,
                                              int e, int chunk, int nbuck) {
    __shared__ int lh[256];
    int tid = threadIdx.x, blk = blockIdx.x;
    lh[tid] = 0;
    __syncthreads();
    int lo = blk * chunk, hi = min(lo + chunk, e);
    for (int i = lo + tid; i < hi; i += 256)
        atomicAdd(&lh[tgt[i] >> 8], 1);
    __syncthreads();
    if (tid < nbuck) gh[tid * NBLK + blk] = lh[tid];
}

// ---------------- scan kernels (cell table; boff folded into consumers) ----------------

__global__ __launch_bounds__(256) void k_scanA(const int* __restrict__ deg,
                                               int* __restrict__ excl,
                                               int* __restrict__ bsum, int n) {
    int i = blockIdx.x * 256 + threadIdx.x;
    int lane = threadIdx.x & 63, wv = threadIdx.x >> 6;
    int v = (i < n) ? deg[i] : 0;
    int incl = v;
#pragma unroll
    for (int off = 1; off < 64; off <<= 1) {
        int t = __shfl_up(incl, off);
        if (lane >= off) incl += t;
    }
    __shared__ int ws[4];
    if (lane == 63) ws[wv] = incl;
    __syncthreads();
    int prefix = 0;
    for (int k = 0; k < wv; ++k) prefix += ws[k];
    if (i < n) excl[i] = prefix + incl - v;
    if (threadIdx.x == 255) bsum[blockIdx.x] = prefix + incl;
}

__global__ __launch_bounds__(256) void k_scanB(const int* __restrict__ bsum, int* __restrict__ boff,
                                               int nb) {
    __shared__ int ws[4];
    __shared__ int carry_s;
    int lane = threadIdx.x & 63, wv = threadIdx.x >> 6;
    if (threadIdx.x == 0) carry_s = 0;
    __syncthreads();
    for (int base = 0; base < nb; base += 256) {
        int i = base + threadIdx.x;
        int v = (i < nb) ? bsum[i] : 0;
        int incl = v;
#pragma unroll
        for (int off = 1; off < 64; off <<= 1) {
            int t = __shfl_up(incl, off);
            if (lane >= off) incl += t;
        }
        if (lane == 63) ws[wv] = incl;
        __syncthreads();
        int prefix = carry_s;
        for (int k = 0; k < wv; ++k) prefix += ws[k];
        if (i < nb) boff[i] = prefix + incl - v;
        __syncthreads();
        if (threadIdx.x == 255) carry_s = prefix + incl;
        __syncthreads();
    }
}

// ---------------- Pass 2: block-dense bucket placement (no global atomics) ----------------

__global__ __launch_bounds__(256) void k_binplace(const int* __restrict__ src,
                                                  const int* __restrict__ tgt,
                                                  const float* __restrict__ ea,
                                                  const float* __restrict__ x,
                                                  const int* __restrict__ gexcl,
                                                  const int* __restrict__ gboff,
                                                  float4* __restrict__ brec,
                                                  int* __restrict__ bmeta,
                                                  int e, int chunk, int nbuck) {
    __shared__ int loff[256];
    int tid = threadIdx.x, blk = blockIdx.x;
    if (tid < nbuck) {
        int cell = tid * NBLK + blk;
        loff[tid] = gexcl[cell] + gboff[cell >> 8];
    }
    __syncthreads();
    int lo = blk * chunk, hi = min(lo + chunk, e);
    for (int i = lo + tid; i < hi; i += 256) {
        int t = tgt[i], s = src[i];
        float2 ev = ((const float2*)ea)[i];
        float2 xv = *(const float2*)(x + 2 * (size_t)s);
        int dst = atomicAdd(&loff[t >> 8], 1);
        brec[dst] = make_float4(xv.x, xv.y, ev.x, ev.y);   // {x[src], ea}
        bmeta[dst] = (s & 0xFFFF) | ((t & 0xFF) << 16);    // src16 | tgt_local8
    }
}

// ---------------- fused: per-bucket degree hist + scan + rowp + CSR placement ----------------

__global__ __launch_bounds__(256) void k_place2(const int* __restrict__ gexcl,
                                                const int* __restrict__ gboff,
                                                const int* __restrict__ bmeta,
                                                const float4* __restrict__ brec,
                                                float4* __restrict__ col_rec,
                                                int* __restrict__ col_src,
                                                int* __restrict__ rowp,
                                                int n, int ntot, int e) {
    __shared__ int hist[256];
    __shared__ int pos[256];
    __shared__ int ws[4];
    int b = blockIdx.x, tid = threadIdx.x;
    int clo = b * NBLK, chi = clo + NBLK;
    int lo = gexcl[clo] + gboff[clo >> 8];
    int hi = (chi >= ntot) ? e : (gexcl[chi] + gboff[chi >> 8]);
    hist[tid] = 0;
    __syncthreads();
    for (int i = lo + tid; i < hi; i += 256)
        atomicAdd(&hist[(bmeta[i] >> 16) & 0xFF], 1);
    __syncthreads();
    int lane = tid & 63, wv = tid >> 6;
    int v = hist[tid];
    int incl = v;
#pragma unroll
    for (int off = 1; off < 64; off <<= 1) {
        int t = __shfl_up(incl, off);
        if (lane >= off) incl += t;
    }
    if (lane == 63) ws[wv] = incl;
    __syncthreads();
    int prefix = 0;
    for (int k = 0; k < wv; ++k) prefix += ws[k];
    int rp = lo + prefix + incl - v;
    int node = b * 256 + tid;
    if (node <= n) rowp[node] = rp;
    if (b == (int)gridDim.x - 1 && tid == 0) rowp[n] = hi;
    pos[tid] = rp;
    __syncthreads();
    for (int i = lo + tid; i < hi; i += 256) {
        int m = bmeta[i];
        float4 r = brec[i];
        int slot = atomicAdd(&pos[(m >> 16) & 0xFF], 1);
        col_rec[slot] = r;
        col_src[slot] = m & 0xFFFF;
    }
}

// ---------------- Layer 1: linearized no-max softmax aggregation ----------------
// wave per node; lane l owns features 2l,2l+1; head = l>>2 (4-lane quad groups).
// Accumulator is linear in the edge record: track px0=SUM(p*x0), px1=SUM(p*x1), lh=SUM(p);
// reconstruct out_f = Wl[0][f]*px0/lh + Wl[1][f]*px1/lh + bl_f in the epilogue.

__global__ __launch_bounds__(256) void k_agg1(
    const float* __restrict__ x,
    const int* __restrict__ rowp,
    const float4* __restrict__ col_rec,
    const float* __restrict__ W_l1, const float* __restrict__ b_l1,
    const float* __restrict__ W_r1, const float* __restrict__ b_r1,
    const float* __restrict__ W_e1,
    const float* __restrict__ att1,
    const float* __restrict__ bias1,
    float* __restrict__ hpost,
    int n)
{
    int wid = (blockIdx.x * blockDim.x + threadIdx.x) >> 6;
    if (wid >= n) return;
    int v = __builtin_amdgcn_readfirstlane(wid);
    int lane = threadIdx.x & 63;
    int f0 = 2 * lane, f1 = 2 * lane + 1;

    float Wl00 = W_l1[f0], Wl10 = W_l1[128 + f0], bl0 = b_l1[f0];
    float Wl01 = W_l1[f1], Wl11 = W_l1[128 + f1], bl1 = b_l1[f1];
    float We00 = W_e1[f0], We10 = W_e1[128 + f0];
    float We01 = W_e1[f1], We11 = W_e1[128 + f1];
    float a0 = att1[f0], a1 = att1[f1];

    float xv0 = x[2 * v], xv1 = x[2 * v + 1];
    // cA/cB = bl + lin_r(x[v]) : constant part of m per feature
    float cA = fmaf(xv0, W_r1[f0], fmaf(xv1, W_r1[128 + f0], b_r1[f0])) + bl0;
    float cB = fmaf(xv0, W_r1[f1], fmaf(xv1, W_r1[128 + f1], b_r1[f1])) + bl1;

    float lh = 0.f, px0 = 0.f, px1 = 0.f;
    int rs = rowp[v], re = rowp[v + 1];
    bool b0 = (lane & 1) != 0, b1 = (lane & 2) != 0;

    int cs = rs;
#define E1(K, R) \
    float s##K; { \
        float m0 = fmaf(R.x, Wl00, fmaf(R.y, Wl10, fmaf(R.z, We00, fmaf(R.w, We10, cA)))); \
        float m1 = fmaf(R.x, Wl01, fmaf(R.y, Wl11, fmaf(R.z, We01, fmaf(R.w, We11, cB)))); \
        s##K = quadsum(fmaf(fmaxf(m0, 0.2f * m0), a0, fmaxf(m1, 0.2f * m1) * a1)); \
    }
    for (; cs + 4 <= re; cs += 4) {
        float4 r0 = col_rec[cs + 0];
        float4 r1 = col_rec[cs + 1];
        float4 r2 = col_rec[cs + 2];
        float4 r3 = col_rec[cs + 3];
        E1(0, r0) E1(1, r1) E1(2, r2) E1(3, r3)
        float sel01 = b0 ? s1 : s0;
        float sel23 = b0 ? s3 : s2;
        float smy = b1 ? sel23 : sel01;     // lane's own edge score (k = lane&3)
        float p = __expf(smy);
        float p0 = dppf<0x00>(p), p1 = dppf<0x55>(p), p2 = dppf<0xAA>(p), p3 = dppf<0xFF>(p);
        lh += (p0 + p1) + (p2 + p3);
        px0 = fmaf(p0, r0.x, px0); px0 = fmaf(p1, r1.x, px0);
        px0 = fmaf(p2, r2.x, px0); px0 = fmaf(p3, r3.x, px0);
        px1 = fmaf(p0, r0.y, px1); px1 = fmaf(p1, r1.y, px1);
        px1 = fmaf(p2, r2.y, px1); px1 = fmaf(p3, r3.y, px1);
    }
#undef E1
    for (; cs < re; ++cs) {                 // tail (<=3 edges); s quad-uniform, no bcast
        float4 r = col_rec[cs];
        float m0 = fmaf(r.x, Wl00, fmaf(r.y, Wl10, fmaf(r.z, We00, fmaf(r.w, We10, cA))));
        float m1 = fmaf(r.x, Wl01, fmaf(r.y, Wl11, fmaf(r.z, We01, fmaf(r.w, We11, cB))));
        float s = quadsum(fmaf(fmaxf(m0, 0.2f * m0), a0, fmaxf(m1, 0.2f * m1) * a1));
        float p = __expf(s);
        lh += p;
        px0 = fmaf(p, r.x, px0);
        px1 = fmaf(p, r.y, px1);
    }

    float r0o = 0.f, r1o = 0.f;
    if (re > rs) {
        float inv = 1.f / lh;
        float q0 = px0 * inv, q1 = px1 * inv;
        r0o = fmaf(q0, Wl00, fmaf(q1, Wl10, bl0));
        r1o = fmaf(q0, Wl01, fmaf(q1, Wl11, bl1));
    }
    r0o += bias1[f0]; r1o += bias1[f1];
    r0o = (r0o > 0.f) ? r0o : (__expf(r0o) - 1.f);
    r1o = (r1o > 0.f) ? r1o : (__expf(r1o) - 1.f);
    *(float2*)(hpost + (size_t)v * 128 + f0) = make_float2(r0o, r1o);
}

// ---------------- Layer 2 node transforms: register-tiled LDS GEMM ----------------

struct XF2Shared {
    float4 hs[64 * 32];
    float4 ws[128 * 16];
};

__device__ __forceinline__ void xf2_pass(XF2Shared& sm,
                                         const float* __restrict__ W,
                                         const float* __restrict__ b,
                                         float* __restrict__ out,
                                         int v0, int n, int t) {
    __syncthreads();
    {
        const float4* wsrc = (const float4*)W;
#pragma unroll
        for (int i = 0; i < 8; ++i) sm.ws[t + 256 * i] = wsrc[t + 256 * i];
    }
    __syncthreads();

    int lane = t & 63, w = t >> 6;
    int fg = lane & 3, ng = lane >> 2;
    int fq = 4 * w + fg;
    int hsw = ng & 7;

    float acc[4][4];
#pragma unroll
    for (int i = 0; i < 4; ++i)
#pragma unroll
        for (int c = 0; c < 4; ++c) acc[i][c] = 0.f;

    for (int kq = 0; kq < 32; ++kq) {
        float4 w0 = sm.ws[(4 * kq + 0) * 16 + fq];
        float4 w1 = sm.ws[(4 * kq + 1) * 16 + fq];
        float4 w2 = sm.ws[(4 * kq + 2) * 16 + fq];
        float4 w3 = sm.ws[(4 * kq + 3) * 16 + fq];
        int ks = kq ^ hsw;
        float4 h0 = sm.hs[(4 * ng + 0) * 32 + ks];
        float4 h1 = sm.hs[(4 * ng + 1) * 32 + ks];
        float4 h2 = sm.hs[(4 * ng + 2) * 32 + ks];
        float4 h3 = sm.hs[(4 * ng + 3) * 32 + ks];
#pragma unroll
        for (int i = 0; i < 4; ++i) {
            float4 h = (i == 0) ? h0 : (i == 1) ? h1 : (i == 2) ? h2 : h3;
            acc[i][0] += h.x * w0.x; acc[i][1] += h.x * w0.y; acc[i][2] += h.x * w0.z; acc[i][3] += h.x * w0.w;
            acc[i][0] += h.y * w1.x; acc[i][1] += h.y * w1.y; acc[i][2] += h.y * w1.z; acc[i][3] += h.y * w1.w;
            acc[i][0] += h.z * w2.x; acc[i][1] += h.z * w2.y; acc[i][2] += h.z * w2.z; acc[i][3] += h.z * w2.w;
            acc[i][0] += h.w * w3.x; acc[i][1] += h.w * w3.y; acc[i][2] += h.w * w3.z; acc[i][3] += h.w * w3.w;
        }
    }

    float4 bf = ((const float4*)b)[fq];
#pragma unroll
    for (int i = 0; i < 4; ++i) {
        int node = v0 + 4 * ng + i;
        if (node < n) {
            float4 r = make_float4(acc[i][0] + bf.x, acc[i][1] + bf.y,
                                   acc[i][2] + bf.z, acc[i][3] + bf.w);
            *(float4*)(out + (size_t)node * 64 + 4 * fq) = r;
        }
    }
}

__global__ __launch_bounds__(256) void k_transform2(
    const float* __restrict__ hpost,
    const float* __restrict__ W_l2, const float* __restrict__ b_l2,
    const float* __restrict__ W_r2, const float* __restrict__ b_r2,
    float* __restrict__ xl2, float* __restrict__ xr2, int n)
{
    __shared__ XF2Shared sm;
    int t = threadIdx.x;
    int v0 = blockIdx.x * 64;
    {
        int node = t >> 2, sub = t & 3;
        int sw = (node >> 2) & 7;
        bool valid = (v0 + node) < n;
        const float4* src = (const float4*)(hpost + (size_t)(v0 + node) * 128);
#pragma unroll
        for (int i = 0; i < 8; ++i) {
            int kq = sub + 4 * i;
            float4 val = valid ? src[kq] : make_float4(0.f, 0.f, 0.f, 0.f);
            sm.hs[node * 32 + (kq ^ sw)] = val;
        }
    }
    xf2_pass(sm, W_l2, b_l2, xl2, v0, n, t);
    xf2_pass(sm, W_r2, b_r2, xr2, v0, n, t);
}

// ---------------- Layer 2 aggregation: no-max softmax ----------------
// wave per node, lane = feature; head = lane>>4 (16-lane groups)

__global__ __launch_bounds__(256) void k_agg2(
    const float* __restrict__ xl2,
    const float* __restrict__ xr2,
    const int* __restrict__ rowp,
    const int* __restrict__ col_src,
    const float4* __restrict__ col_rec,
    const float* __restrict__ W_e2,
    const float* __restrict__ att2,
    const float* __restrict__ bias2,
    float* __restrict__ h2,
    int n)
{
    int wid = (blockIdx.x * blockDim.x + threadIdx.x) >> 6;
    if (wid >= n) return;
    int v = __builtin_amdgcn_readfirstlane(wid);
    int lane = threadIdx.x & 63;
    float We0 = W_e2[lane], We1 = W_e2[64 + lane];
    float a = att2[lane];
    float xr = xr2[(size_t)v * 64 + lane];
    float lh = 0.f, acc = 0.f;
    int rs = rowp[v], re = rowp[v + 1];
    const float2* eap = (const float2*)col_rec;   // {ea0,ea1} at odd float2 slots
    bool b0 = (lane & 1) != 0, b1 = (lane & 2) != 0;

    int cs = rs;
#define E2(K, EV, XL) \
    float s##K; { \
        float m = fmaf(EV.x, We0, fmaf(EV.y, We1, XL + xr)); \
        s##K = sum16(fmaxf(m, 0.2f * m) * a); \
    }
    for (; cs + 4 <= re; cs += 4) {
        int u0 = col_src[cs], u1 = col_src[cs + 1], u2 = col_src[cs + 2], u3 = col_src[cs + 3];
        float2 e0 = eap[2 * cs + 1], e1 = eap[2 * cs + 3];
        float2 e2 = eap[2 * cs + 5], e3 = eap[2 * cs + 7];
        float xl0 = xl2[(size_t)u0 * 64 + lane];
        float xl1 = xl2[(size_t)u1 * 64 + lane];
        float xl2_ = xl2[(size_t)u2 * 64 + lane];
        float xl3 = xl2[(size_t)u3 * 64 + lane];
        E2(0, e0, xl0) E2(1, e1, xl1) E2(2, e2, xl2_) E2(3, e3, xl3)
        float sel01 = b0 ? s1 : s0;
        float sel23 = b0 ? s3 : s2;
        float smy = b1 ? sel23 : sel01;
        float p = __expf(smy);
        float p0 = dppf<0x00>(p), p1 = dppf<0x55>(p), p2 = dppf<0xAA>(p), p3 = dppf<0xFF>(p);
        lh += (p0 + p1) + (p2 + p3);
        acc = fmaf(p0, xl0, acc); acc = fmaf(p1, xl1, acc);
        acc = fmaf(p2, xl2_, acc); acc = fmaf(p3, xl3, acc);
    }
#undef E2
    for (; cs < re; ++cs) {
        int u = col_src[cs];
        float2 ev = eap[2 * cs + 1];
        float xl = xl2[(size_t)u * 64 + lane];
        float m = fmaf(ev.x, We0, fmaf(ev.y, We1, xl + xr));
        float s = sum16(fmaxf(m, 0.2f * m) * a);
        float p = __expf(s);
        lh += p;
        acc = fmaf(p, xl, acc);
    }
    float r = (re > rs) ? acc / lh : 0.f;
    h2[(size_t)v * 64 + lane] = r + bias2[lane];
}

// ---------------- Mean pool over graphs (batch sorted: segmented reduce) ----------------

__global__ __launch_bounds__(256) void k_pool2(const float* __restrict__ h2,
                                               const int* __restrict__ batch,
                                               float* __restrict__ sums, float* __restrict__ cnt,
                                               int n, int chunk) {
    int w = (blockIdx.x * blockDim.x + threadIdx.x) >> 6;
    int lane = threadIdx.x & 63;
    int start = w * chunk;
    if (start >= n) return;
    int end = min(n, start + chunk);
    int g = batch[start];
    float acc = 0.f;
    int c = 0;
    for (int v = start; v < end; ++v) {
        int bg = batch[v];
        if (bg != g) {
            atomicAdd(&sums[g * 64 + lane], acc);
            if (lane == 0) atomicAdd(&cnt[g], (float)c);
            acc = 0.f; c = 0; g = bg;
        }
        acc += h2[(size_t)v * 64 + lane];
        ++c;
    }
    atomicAdd(&sums[g * 64 + lane], acc);
    if (lane == 0) atomicAdd(&cnt[g], (float)c);
}

__global__ void k_final(const float* __restrict__ sums, const float* __restrict__ cnt,
                        float* __restrict__ out, int g) {
    int i = blockIdx.x * blockDim.x + threadIdx.x;
    if (i < g * 64) out[i] = sums[i] / fmaxf(cnt[i >> 6], 1.f);
}

// ---------------- launch ----------------

extern "C" void kernel_launch(void* const* d_in, const int* in_sizes, int n_in,
                              void* d_out, int out_size, void* d_ws, size_t ws_size,
                              hipStream_t stream) {
    const float* x     = (const float*)d_in[0];
    const float* ea    = (const float*)d_in[1];
    const float* W_l1  = (const float*)d_in[2];
    const float* b_l1  = (const float*)d_in[3];
    const float* W_r1  = (const float*)d_in[4];
    const float* b_r1  = (const float*)d_in[5];
    const float* W_e1  = (const float*)d_in[6];
    const float* att1  = (const float*)d_in[7];
    const float* bias1 = (const float*)d_in[8];
    const float* W_l2  = (const float*)d_in[9];
    const float* b_l2  = (const float*)d_in[10];
    const float* W_r2  = (const float*)d_in[11];
    const float* b_r2  = (const float*)d_in[12];
    const float* W_e2  = (const float*)d_in[13];
    const float* att2  = (const float*)d_in[14];
    const float* bias2 = (const float*)d_in[15];
    const int* eidx    = (const int*)d_in[16];
    const int* batch   = (const int*)d_in[17];

    int n = in_sizes[0] / 2;     // 50000
    int e = in_sizes[16] / 2;    // 800000
    int g = out_size / 64;       // 64
    const int* srcI = eidx;
    const int* tgtI = eidx + e;
    int nb = (n + 255) / 256;    // 196 buckets (256 nodes each)
    int ntot = nb * NBLK;        // cell table size
    int nb2 = (ntot + 255) / 256;
    int chunk = (e + NBLK - 1) / NBLK;

    char* w = (char*)d_ws;
    size_t off = 0;
    auto take = [&](size_t bytes) -> char* {
        size_t a = (off + 255) & ~(size_t)255;
        off = a + bytes;
        return w + a;
    };
    // region1: brec (sort phase) then hpost (agg1..transform2) then h2 (agg2..pool)
    char*   reg1    = take((size_t)n * 128 * 4);        // 25.6 MB >= e*16
    float4* brec    = (float4*)reg1;
    float*  hpost   = (float*)reg1;
    float*  h2      = hpost;
    // region2: bmeta (sort phase) then xl2 (transform2..agg2)
    char*   reg2    = take((size_t)n * 64 * 4);         // 12.8 MB >= e*4
    int*    bmeta   = (int*)reg2;
    float*  xl2     = (float*)reg2;

    float*  xr2     = (float*)take((size_t)n * 64 * 4);
    float4* col_rec = (float4*)take((size_t)e * 16);
    int*    col_src = (int*)take((size_t)e * 4);
    int*    rowp    = (int*)take((size_t)(n + 1) * 4);
    int*    gh      = (int*)take((size_t)ntot * 4);
    int*    gexcl   = (int*)take((size_t)(ntot + 1) * 4);
    int*    gbsum   = (int*)take((size_t)nb2 * 4);
    int*    gboff   = (int*)take((size_t)nb2 * 4);
    float*  sums    = (float*)take((size_t)g * 64 * 4);
    float*  cnt     = (float*)take((size_t)g * 4);

    k_init<<<(g * 64 + 255) / 256, 256, 0, stream>>>(sums, cnt, g);

    // dense two-pass counting sort by (bucket, block)
    k_hist<<<NBLK, 256, 0, stream>>>(tgtI, gh, e, chunk, nb);
    k_scanA<<<nb2, 256, 0, stream>>>(gh, gexcl, gbsum, ntot);
    k_scanB<<<1, 256, 0, stream>>>(gbsum, gboff, nb2);
    k_binplace<<<NBLK, 256, 0, stream>>>(srcI, tgtI, ea, x, gexcl, gboff, brec, bmeta,
                                         e, chunk, nb);
    k_place2<<<nb, 256, 0, stream>>>(gexcl, gboff, bmeta, brec, col_rec, col_src, rowp,
                                     n, ntot, e);

    int nwaveblocks = (n * 64 + 255) / 256;
    k_agg1<<<nwaveblocks, 256, 0, stream>>>(x, rowp, col_rec,
                                            W_l1, b_l1, W_r1, b_r1, W_e1, att1, bias1,
                                            hpost, n);
    int ntiles = (n + 63) / 64;
    k_transform2<<<ntiles, 256, 0, stream>>>(hpost, W_l2, b_l2, W_r2, b_r2, xl2, xr2, n);
    k_agg2<<<nwaveblocks, 256, 0, stream>>>(xl2, xr2, rowp, col_src, col_rec,
                                            W_e2, att2, bias2, h2, n);

    int pool_waves = 1024;
    int pool_chunk = (n + pool_waves - 1) / pool_waves;
    k_pool2<<<pool_waves / 4, 256, 0, stream>>>(h2, batch, sums, cnt, n, pool_chunk);
    k_final<<<(g * 64 + 255) / 256, 256, 0, stream>>>(sums, cnt, (float*)d_out, g);
}